// Round 4
// baseline (505.067 us; speedup 1.0000x reference)
//
#include <hip/hip_runtime.h>
#include <stdint.h>

#define N_ANCH 67200
#define KCAP   1000
#define CONF_THR 0.7f
#define NMS_THR  0.4f

// score-bits histogram: scores in (0.7, 1.0) -> bits in (0x3F333333, 0x3F800000)
#define BUCK_BASE 0x3F333333u
#define BUCK_SHIFT 8
#define NBUCK 1280            // covers span 0x4CCCD>>8 = 1228, padded to 20*64
#define CAP2 32768            // capacity of filtered candidate set

// ---- workspace layout (bytes) ----
#define OFF_CTR   0           // int[0]=M, int[1]=M2, int[2]=cut bucket B
#define OFF_HIST  64          // NBUCK*4 = 5120 -> 5184
#define OFF_KEYS  5184        // N_ANCH*8 = 537600 -> 542784
#define OFF_KEYS2 542784      // CAP2*8 = 262144 -> 804928
#define OFF_SCORE 804928      // 1024*4 -> 809024
#define OFF_BOX   809024      // 1024*16 -> 825408 (16B aligned)
#define OFF_LM    825408      // 1024*40 -> 866368
#define OFF_SUP   866368      // 1000*16*8 = 128000 -> 994368

__device__ inline unsigned long long shfl_xor_u64(unsigned long long v, int m) {
    unsigned int lo = (unsigned int)__shfl_xor((int)(v & 0xffffffffull), m, 64);
    unsigned int hi = (unsigned int)__shfl_xor((int)(v >> 32), m, 64);
    return ((unsigned long long)hi << 32) | lo;
}

// K1: softmax score, threshold, compact candidates into 64-bit sortable keys
// + histogram of score bits. key = (score_bits<<32) | (0xFFFFFFFF - index):
// descending key order == top_k order (ties -> ascending index).
__global__ void k_score_compact(const float* __restrict__ conf,
                                unsigned long long* __restrict__ keys,
                                int* __restrict__ hist,
                                int* __restrict__ ctr) {
    int i = blockIdx.x * blockDim.x + threadIdx.x;
    if (i >= N_ANCH) return;
    float c0 = conf[2*i+0];
    float c1 = conf[2*i+1];
    float m  = fmaxf(c0, c1);
    float e0 = expf(c0 - m);
    float e1 = expf(c1 - m);
    float s  = e1 / (e0 + e1);
    if (s > CONF_THR) {
        unsigned int sb = __float_as_uint(s);
        int pos = atomicAdd(&ctr[0], 1);
        keys[pos] = ((unsigned long long)sb << 32)
                  | (unsigned int)(0xFFFFFFFFu - (unsigned int)i);
        int b = min((int)((sb - BUCK_BASE) >> BUCK_SHIFT), NBUCK - 1);
        atomicAdd(&hist[b], 1);
    }
}

// K2: find cut bucket B = largest b such that count(buckets >= b) >= KCAP
// (or 0 if total < KCAP). Wave 0 scans chunks of 64 from the top; scalar
// in-chunk resolve via readlane (wave-uniform).
__global__ __launch_bounds__(1024) void k_findcut(const int* __restrict__ hist,
                                                  int* __restrict__ ctr) {
    __shared__ int sh[NBUCK];
    int tid = threadIdx.x;
    for (int t = tid; t < NBUCK; t += 1024) sh[t] = hist[t];
    __syncthreads();
    if (tid >= 64) return;
    int lane = tid;
    int acc = 0, B = 0;
    bool found = false;
    for (int t = 0; t < NBUCK / 64 && !found; ++t) {
        int base = NBUCK - 64 * (t + 1);
        int c = sh[base + lane];
        int ssum = c;
#pragma unroll
        for (int off = 1; off < 64; off <<= 1)
            ssum += __shfl_xor(ssum, off, 64);
        if (acc + ssum >= KCAP) {
            for (int l = 63; l >= 0; --l) {
                int cl = (int)__builtin_amdgcn_readlane((unsigned int)c, l);
                if (acc + cl >= KCAP) { B = base + l; found = true; break; }
                acc += cl;
            }
        } else {
            acc += ssum;
        }
    }
    if (lane == 0) ctr[2] = found ? B : 0;
}

// K3: compact candidates with bucket >= B into keys2.
__global__ void k_compact2(const unsigned long long* __restrict__ keys,
                           unsigned long long* __restrict__ keys2,
                           int* __restrict__ ctr) {
    int M = ctr[0];
    int B = ctr[2];
    int p = blockIdx.x * blockDim.x + threadIdx.x;
    if (p >= M) return;
    unsigned long long k = keys[p];
    unsigned int sb = (unsigned int)(k >> 32);
    int b = min((int)((sb - BUCK_BASE) >> BUCK_SHIFT), NBUCK - 1);
    if (b >= B) {
        int pos = atomicAdd(&ctr[1], 1);
        if (pos < CAP2) keys2[pos] = k;
    }
}

// K4: exact rank over the filtered set (== global rank, since every excluded
// key is strictly smaller), then decode box+landmarks straight into slot r.
__global__ void k_rank_select(const unsigned long long* __restrict__ keys2,
                              const int* __restrict__ ctr,
                              const float* __restrict__ loc,
                              const float* __restrict__ land,
                              const float* __restrict__ priors,
                              float* __restrict__ sel_score,
                              float* __restrict__ sel_box,
                              float* __restrict__ sel_lm) {
#pragma clang fp contract(off)
    int M2 = min(ctr[1], CAP2);
    if ((int)(blockIdx.x * blockDim.x) >= M2) return;
    int p = blockIdx.x * blockDim.x + threadIdx.x;
    __shared__ unsigned long long sk[256];
    unsigned long long mykey = (p < M2) ? keys2[p] : 0ull;
    int cnt = 0;
    for (int j0 = 0; j0 < M2; j0 += 256) {
        int idx = j0 + threadIdx.x;
        sk[threadIdx.x] = (idx < M2) ? keys2[idx] : 0ull;
        __syncthreads();
        int lim = min(256, M2 - j0);
#pragma unroll 8
        for (int t = 0; t < lim; ++t)
            cnt += (sk[t] > mykey) ? 1 : 0;
        __syncthreads();
    }
    if (p >= M2 || cnt >= KCAP) return;
    int r = cnt;
    unsigned int a = 0xFFFFFFFFu - (unsigned int)(mykey & 0xFFFFFFFFull);
    sel_score[r] = __uint_as_float((unsigned int)(mykey >> 32));

    float pcx = priors[a*4+0], pcy = priors[a*4+1];
    float pw  = priors[a*4+2], ph  = priors[a*4+3];
    float l0 = loc[a*4+0], l1 = loc[a*4+1], l2 = loc[a*4+2], l3 = loc[a*4+3];
    // replicate reference op order exactly:
    float cx = pcx + (l0 * 0.1f) * pw;
    float cy = pcy + (l1 * 0.1f) * ph;
    float w  = pw * expf(l2 * 0.2f);
    float h  = ph * expf(l3 * 0.2f);
    float x1 = cx - w * 0.5f;
    float y1 = cy - h * 0.5f;
    sel_box[r*4+0] = x1 * 1280.0f;
    sel_box[r*4+1] = y1 * 1280.0f;
    sel_box[r*4+2] = (x1 + w) * 1280.0f;
    sel_box[r*4+3] = (y1 + h) * 1280.0f;
#pragma unroll
    for (int q = 0; q < 5; ++q) {
        float lx = land[a*10 + 2*q + 0];
        float ly = land[a*10 + 2*q + 1];
        sel_lm[r*10 + 2*q + 0] = (pcx + (lx * 0.1f) * pw) * 1280.0f;
        sel_lm[r*10 + 2*q + 1] = (pcy + (ly * 0.1f) * ph) * 1280.0f;
    }
}

// K5: suppression bitmask rows. sup[i][g] bit l set iff j=g*64+l satisfies
// j>i, both valid, iou(b_i,b_j) > NMS_THR.
__global__ void k_sup(const float* __restrict__ sel_box,
                      const int* __restrict__ ctr,
                      unsigned long long* __restrict__ sup) {
#pragma clang fp contract(off)
    int i = blockIdx.x;
    int V = min(min(ctr[1], CAP2), KCAP);
    int lane = threadIdx.x; // 64 threads
    float ax1 = 0.f, ay1 = 0.f, ax2 = 0.f, ay2 = 0.f, aarea = 0.f;
    bool irow = (i < V);
    if (irow) {
        ax1 = sel_box[i*4+0]; ay1 = sel_box[i*4+1];
        ax2 = sel_box[i*4+2]; ay2 = sel_box[i*4+3];
        aarea = (ax2 - ax1) * (ay2 - ay1);
    }
    for (int g = 0; g < 16; ++g) {
        int j = g * 64 + lane;
        bool pred = false;
        if (irow && j < V && j > i) {
            float4 b = reinterpret_cast<const float4*>(sel_box)[j];
            float barea = (b.z - b.x) * (b.w - b.y);
            float ltx = fmaxf(ax1, b.x), lty = fmaxf(ay1, b.y);
            float rbx = fminf(ax2, b.z), rby = fminf(ay2, b.w);
            float wx = fmaxf(rbx - ltx, 0.0f);
            float wy = fmaxf(rby - lty, 0.0f);
            float inter = wx * wy;
            float iou = inter / (aarea + barea - inter + 1e-12f);
            pred = iou > NMS_THR;
        }
        unsigned long long mask = __ballot(pred);
        if (lane == 0) sup[i*16 + g] = mask;
    }
}

// K6: blocked greedy NMS scan (exact forward substitution) + output write.
// Wave c resolves chunk c's 64x64 recurrence on the scalar pipe; later waves
// apply kept rows via shfl_xor OR-butterfly. XOR-swizzled LDS layout.
// NOTE: readlane/readfirstlane return int; widen through unsigned int.
__global__ __launch_bounds__(1024) void k_nms_scan(
        const unsigned long long* __restrict__ sup,
        const int* __restrict__ ctr,
        const float* __restrict__ sel_score,
        const float* __restrict__ sel_box,
        const float* __restrict__ sel_lm,
        float* __restrict__ out) {
    __shared__ unsigned long long sup_r[1024][16]; // [row][w ^ (row&15)]
    __shared__ unsigned long long mshare[16];
    __shared__ unsigned long long keep_final[16];
    int tid = threadIdx.x;
    int wave = tid >> 6, lane = tid & 63;
    int V = min(min(ctr[1], CAP2), KCAP);

    for (int idx = tid; idx < KCAP * 16; idx += 1024) {
        int r = idx >> 4, w = idx & 15;
        sup_r[r][w ^ (r & 15)] = sup[idx];
    }
    if (tid < 24 * 16) { // zero rows 1000..1023
        int r = 1000 + (tid >> 4), w = tid & 15;
        sup_r[r][w ^ (r & 15)] = 0ull;
    }
    unsigned long long kw;
    {
        int lo = wave * 64;
        kw = (V >= lo + 64) ? ~0ull : (V <= lo ? 0ull : ((1ull << (V - lo)) - 1ull));
    }
    __syncthreads();

    for (int c = 0; c < 16; ++c) {
        if (wave == c) {
            unsigned long long drow = sup_r[c*64 + lane][c ^ (lane & 15)];
            unsigned int dlo = (unsigned int)drow;
            unsigned int dhi = (unsigned int)(drow >> 32);
            unsigned long long m =
                (((unsigned long long)(unsigned int)__builtin_amdgcn_readfirstlane((unsigned int)(kw >> 32))) << 32)
              |  (unsigned long long)(unsigned int)__builtin_amdgcn_readfirstlane((unsigned int)kw);
#pragma unroll
            for (int i = 0; i < 64; ++i) {
                unsigned long long di =
                    (((unsigned long long)(unsigned int)__builtin_amdgcn_readlane(dhi, i)) << 32)
                  |  (unsigned long long)(unsigned int)__builtin_amdgcn_readlane(dlo, i);
                m = ((m >> i) & 1ull) ? (m & ~di) : m;
            }
            kw = m;
            if (lane == 0) mshare[c] = m;
        }
        __syncthreads();
        if (wave > c) {
            unsigned long long m = mshare[c];
            unsigned long long contrib = ((m >> lane) & 1ull)
                ? sup_r[c*64 + lane][wave ^ (lane & 15)] : 0ull;
#pragma unroll
            for (int off = 1; off < 64; off <<= 1)
                contrib |= shfl_xor_u64(contrib, off);
            kw &= ~contrib;
        }
    }
    if (lane == 0) keep_final[wave] = kw;
    __syncthreads();

    // write outputs: boxes [0,4000), scores [4000,5000), landms [5000,15000)
    for (int s = tid; s < KCAP; s += 1024) {
        bool kept = ((keep_final[s >> 6] >> (s & 63)) & 1ull) != 0ull;
        float4 b = make_float4(0.f, 0.f, 0.f, 0.f);
        float sc = 0.f;
        if (kept) {
            b  = reinterpret_cast<const float4*>(sel_box)[s];
            sc = sel_score[s];
        }
        reinterpret_cast<float4*>(out)[s] = b;
        out[4000 + s] = sc;
#pragma unroll
        for (int q = 0; q < 10; ++q)
            out[5000 + s*10 + q] = kept ? sel_lm[s*10 + q] : 0.f;
    }
}

extern "C" void kernel_launch(void* const* d_in, const int* in_sizes, int n_in,
                              void* d_out, int out_size, void* d_ws, size_t ws_size,
                              hipStream_t stream) {
    const float* loc    = (const float*)d_in[0];
    const float* conf   = (const float*)d_in[1];
    const float* land   = (const float*)d_in[2];
    const float* priors = (const float*)d_in[3];
    float* out = (float*)d_out;
    char* ws = (char*)d_ws;

    int* ctr                     = (int*)(ws + OFF_CTR);
    int* hist                    = (int*)(ws + OFF_HIST);
    unsigned long long* keys     = (unsigned long long*)(ws + OFF_KEYS);
    unsigned long long* keys2    = (unsigned long long*)(ws + OFF_KEYS2);
    float* sel_score             = (float*)(ws + OFF_SCORE);
    float* sel_box               = (float*)(ws + OFF_BOX);
    float* sel_lm                = (float*)(ws + OFF_LM);
    unsigned long long* sup      = (unsigned long long*)(ws + OFF_SUP);

    hipMemsetAsync(ws, 0, OFF_KEYS, stream); // zero counters + histogram

    int nb = (N_ANCH + 255) / 256; // 263
    k_score_compact<<<nb, 256, 0, stream>>>(conf, keys, hist, ctr);
    k_findcut<<<1, 1024, 0, stream>>>(hist, ctr);
    k_compact2<<<nb, 256, 0, stream>>>(keys, keys2, ctr);
    k_rank_select<<<CAP2 / 256, 256, 0, stream>>>(keys2, ctr, loc, land, priors,
                                                  sel_score, sel_box, sel_lm);
    k_sup<<<KCAP, 64, 0, stream>>>(sel_box, ctr, sup);
    k_nms_scan<<<1, 1024, 0, stream>>>(sup, ctr, sel_score, sel_box, sel_lm, out);
}

// Round 5
// 98.072 us; speedup vs baseline: 5.1500x; 5.1500x over previous
//
#include <hip/hip_runtime.h>
#include <stdint.h>

#define N_ANCH 67200
#define KCAP   1000
#define CONF_THR 0.7f
#define NMS_THR  0.4f

// score-bits histogram: scores in (0.7, 1.0) -> bits in (0x3F333333, 0x3F800000)
// span = 0x4CCCCD = 5,033,165 ulp  (round-4 bug: was mis-computed as 0x4CCCD).
// shift 10 -> 4916 live buckets; NBUCK = 4992 = 78*64 covers with headroom.
#define BUCK_BASE 0x3F333333u
#define BUCK_SHIFT 10
#define NBUCK 4992
#define CAP2 16384            // capacity of filtered candidate set (M2 ~ 1010)

// ---- workspace layout (bytes) ----
#define OFF_CTR   0           // int[0]=M, int[1]=M2, int[2]=cut bucket B
#define OFF_HIST  64          // NBUCK*4 = 19968 -> 20032
#define OFF_KEYS  20032       // N_ANCH*8 = 537600 -> 557632
#define OFF_KEYS2 557632      // CAP2*8 = 131072 -> 688704
#define OFF_SCORE 688704      // 1024*4 -> 692800
#define OFF_BOX   692800      // 1024*16 -> 709184 (16B aligned)
#define OFF_LM    709184      // 1024*40 -> 750144
#define OFF_SUP   750144      // 1000*16*8 = 128000 -> 878144 (~0.84 MB total)

__device__ inline unsigned long long shfl_xor_u64(unsigned long long v, int m) {
    unsigned int lo = (unsigned int)__shfl_xor((int)(v & 0xffffffffull), m, 64);
    unsigned int hi = (unsigned int)__shfl_xor((int)(v >> 32), m, 64);
    return ((unsigned long long)hi << 32) | lo;
}

// K1: softmax score, threshold, compact candidates into 64-bit sortable keys
// + histogram of score bits. key = (score_bits<<32) | (0xFFFFFFFF - index):
// descending key order == top_k order (ties -> ascending index).
__global__ void k_score_compact(const float* __restrict__ conf,
                                unsigned long long* __restrict__ keys,
                                int* __restrict__ hist,
                                int* __restrict__ ctr) {
    int i = blockIdx.x * blockDim.x + threadIdx.x;
    if (i >= N_ANCH) return;
    float c0 = conf[2*i+0];
    float c1 = conf[2*i+1];
    float m  = fmaxf(c0, c1);
    float e0 = expf(c0 - m);
    float e1 = expf(c1 - m);
    float s  = e1 / (e0 + e1);
    if (s > CONF_THR) {
        unsigned int sb = __float_as_uint(s);
        int pos = atomicAdd(&ctr[0], 1);
        keys[pos] = ((unsigned long long)sb << 32)
                  | (unsigned int)(0xFFFFFFFFu - (unsigned int)i);
        int b = min((int)((sb - BUCK_BASE) >> BUCK_SHIFT), NBUCK - 1);
        atomicAdd(&hist[b], 1);
    }
}

// K2: find cut bucket B = largest b such that count(buckets >= b) >= KCAP
// (or 0 if total < KCAP). Wave 0 scans 64-bucket chunks from the top; scalar
// in-chunk resolve via readlane (all wave-uniform).
__global__ __launch_bounds__(1024) void k_findcut(const int* __restrict__ hist,
                                                  int* __restrict__ ctr) {
    __shared__ int sh[NBUCK];
    int tid = threadIdx.x;
    for (int t = tid; t < NBUCK; t += 1024) sh[t] = hist[t];
    __syncthreads();
    if (tid >= 64) return;
    int lane = tid;
    int acc = 0, B = 0;
    bool found = false;
    for (int t = 0; t < NBUCK / 64 && !found; ++t) {
        int base = NBUCK - 64 * (t + 1);
        int c = sh[base + lane];
        int ssum = c;
#pragma unroll
        for (int off = 1; off < 64; off <<= 1)
            ssum += __shfl_xor(ssum, off, 64);
        if (acc + ssum >= KCAP) {
            for (int l = 63; l >= 0; --l) {
                int cl = (int)__builtin_amdgcn_readlane((unsigned int)c, l);
                if (acc + cl >= KCAP) { B = base + l; found = true; break; }
                acc += cl;
            }
        } else {
            acc += ssum;
        }
    }
    if (lane == 0) ctr[2] = found ? B : 0;
}

// K3: compact candidates with bucket >= B into keys2.
__global__ void k_compact2(const unsigned long long* __restrict__ keys,
                           unsigned long long* __restrict__ keys2,
                           int* __restrict__ ctr) {
    int M = ctr[0];
    int B = ctr[2];
    int p = blockIdx.x * blockDim.x + threadIdx.x;
    if (p >= M) return;
    unsigned long long k = keys[p];
    unsigned int sb = (unsigned int)(k >> 32);
    int b = min((int)((sb - BUCK_BASE) >> BUCK_SHIFT), NBUCK - 1);
    if (b >= B) {
        int pos = atomicAdd(&ctr[1], 1);
        if (pos < CAP2) keys2[pos] = k;
    }
}

// K4: exact rank over the filtered set (== global rank, since every excluded
// key is strictly smaller), then decode box+landmarks straight into slot r.
__global__ void k_rank_select(const unsigned long long* __restrict__ keys2,
                              const int* __restrict__ ctr,
                              const float* __restrict__ loc,
                              const float* __restrict__ land,
                              const float* __restrict__ priors,
                              float* __restrict__ sel_score,
                              float* __restrict__ sel_box,
                              float* __restrict__ sel_lm) {
#pragma clang fp contract(off)
    int M2 = min(ctr[1], CAP2);
    if ((int)(blockIdx.x * blockDim.x) >= M2) return;
    int p = blockIdx.x * blockDim.x + threadIdx.x;
    __shared__ unsigned long long sk[256];
    unsigned long long mykey = (p < M2) ? keys2[p] : 0ull;
    int cnt = 0;
    for (int j0 = 0; j0 < M2; j0 += 256) {
        int idx = j0 + threadIdx.x;
        sk[threadIdx.x] = (idx < M2) ? keys2[idx] : 0ull;
        __syncthreads();
        int lim = min(256, M2 - j0);
#pragma unroll 8
        for (int t = 0; t < lim; ++t)
            cnt += (sk[t] > mykey) ? 1 : 0;
        __syncthreads();
    }
    if (p >= M2 || cnt >= KCAP) return;
    int r = cnt;
    unsigned int a = 0xFFFFFFFFu - (unsigned int)(mykey & 0xFFFFFFFFull);
    sel_score[r] = __uint_as_float((unsigned int)(mykey >> 32));

    float pcx = priors[a*4+0], pcy = priors[a*4+1];
    float pw  = priors[a*4+2], ph  = priors[a*4+3];
    float l0 = loc[a*4+0], l1 = loc[a*4+1], l2 = loc[a*4+2], l3 = loc[a*4+3];
    // replicate reference op order exactly:
    float cx = pcx + (l0 * 0.1f) * pw;
    float cy = pcy + (l1 * 0.1f) * ph;
    float w  = pw * expf(l2 * 0.2f);
    float h  = ph * expf(l3 * 0.2f);
    float x1 = cx - w * 0.5f;
    float y1 = cy - h * 0.5f;
    sel_box[r*4+0] = x1 * 1280.0f;
    sel_box[r*4+1] = y1 * 1280.0f;
    sel_box[r*4+2] = (x1 + w) * 1280.0f;
    sel_box[r*4+3] = (y1 + h) * 1280.0f;
#pragma unroll
    for (int q = 0; q < 5; ++q) {
        float lx = land[a*10 + 2*q + 0];
        float ly = land[a*10 + 2*q + 1];
        sel_lm[r*10 + 2*q + 0] = (pcx + (lx * 0.1f) * pw) * 1280.0f;
        sel_lm[r*10 + 2*q + 1] = (pcy + (ly * 0.1f) * ph) * 1280.0f;
    }
}

// K5: suppression bitmask rows. sup[i][g] bit l set iff j=g*64+l satisfies
// j>i, both valid, iou(b_i,b_j) > NMS_THR.
__global__ void k_sup(const float* __restrict__ sel_box,
                      const int* __restrict__ ctr,
                      unsigned long long* __restrict__ sup) {
#pragma clang fp contract(off)
    int i = blockIdx.x;
    int V = min(min(ctr[1], CAP2), KCAP);
    int lane = threadIdx.x; // 64 threads
    float ax1 = 0.f, ay1 = 0.f, ax2 = 0.f, ay2 = 0.f, aarea = 0.f;
    bool irow = (i < V);
    if (irow) {
        ax1 = sel_box[i*4+0]; ay1 = sel_box[i*4+1];
        ax2 = sel_box[i*4+2]; ay2 = sel_box[i*4+3];
        aarea = (ax2 - ax1) * (ay2 - ay1);
    }
    for (int g = 0; g < 16; ++g) {
        int j = g * 64 + lane;
        bool pred = false;
        if (irow && j < V && j > i) {
            float4 b = reinterpret_cast<const float4*>(sel_box)[j];
            float barea = (b.z - b.x) * (b.w - b.y);
            float ltx = fmaxf(ax1, b.x), lty = fmaxf(ay1, b.y);
            float rbx = fminf(ax2, b.z), rby = fminf(ay2, b.w);
            float wx = fmaxf(rbx - ltx, 0.0f);
            float wy = fmaxf(rby - lty, 0.0f);
            float inter = wx * wy;
            float iou = inter / (aarea + barea - inter + 1e-12f);
            pred = iou > NMS_THR;
        }
        unsigned long long mask = __ballot(pred);
        if (lane == 0) sup[i*16 + g] = mask;
    }
}

// K6: blocked greedy NMS scan (exact forward substitution) + output write.
// Wave c resolves chunk c's 64x64 recurrence on the scalar pipe; later waves
// apply kept rows via shfl_xor OR-butterfly. XOR-swizzled LDS layout.
// NOTE: readlane/readfirstlane return int; widen through unsigned int.
__global__ __launch_bounds__(1024) void k_nms_scan(
        const unsigned long long* __restrict__ sup,
        const int* __restrict__ ctr,
        const float* __restrict__ sel_score,
        const float* __restrict__ sel_box,
        const float* __restrict__ sel_lm,
        float* __restrict__ out) {
    __shared__ unsigned long long sup_r[1024][16]; // [row][w ^ (row&15)]
    __shared__ unsigned long long mshare[16];
    __shared__ unsigned long long keep_final[16];
    int tid = threadIdx.x;
    int wave = tid >> 6, lane = tid & 63;
    int V = min(min(ctr[1], CAP2), KCAP);

    for (int idx = tid; idx < KCAP * 16; idx += 1024) {
        int r = idx >> 4, w = idx & 15;
        sup_r[r][w ^ (r & 15)] = sup[idx];
    }
    if (tid < 24 * 16) { // zero rows 1000..1023
        int r = 1000 + (tid >> 4), w = tid & 15;
        sup_r[r][w ^ (r & 15)] = 0ull;
    }
    unsigned long long kw;
    {
        int lo = wave * 64;
        kw = (V >= lo + 64) ? ~0ull : (V <= lo ? 0ull : ((1ull << (V - lo)) - 1ull));
    }
    __syncthreads();

    for (int c = 0; c < 16; ++c) {
        if (wave == c) {
            unsigned long long drow = sup_r[c*64 + lane][c ^ (lane & 15)];
            unsigned int dlo = (unsigned int)drow;
            unsigned int dhi = (unsigned int)(drow >> 32);
            unsigned long long m =
                (((unsigned long long)(unsigned int)__builtin_amdgcn_readfirstlane((unsigned int)(kw >> 32))) << 32)
              |  (unsigned long long)(unsigned int)__builtin_amdgcn_readfirstlane((unsigned int)kw);
#pragma unroll
            for (int i = 0; i < 64; ++i) {
                unsigned long long di =
                    (((unsigned long long)(unsigned int)__builtin_amdgcn_readlane(dhi, i)) << 32)
                  |  (unsigned long long)(unsigned int)__builtin_amdgcn_readlane(dlo, i);
                m = ((m >> i) & 1ull) ? (m & ~di) : m;
            }
            kw = m;
            if (lane == 0) mshare[c] = m;
        }
        __syncthreads();
        if (wave > c) {
            unsigned long long m = mshare[c];
            unsigned long long contrib = ((m >> lane) & 1ull)
                ? sup_r[c*64 + lane][wave ^ (lane & 15)] : 0ull;
#pragma unroll
            for (int off = 1; off < 64; off <<= 1)
                contrib |= shfl_xor_u64(contrib, off);
            kw &= ~contrib;
        }
    }
    if (lane == 0) keep_final[wave] = kw;
    __syncthreads();

    // write outputs: boxes [0,4000), scores [4000,5000), landms [5000,15000)
    for (int s = tid; s < KCAP; s += 1024) {
        bool kept = ((keep_final[s >> 6] >> (s & 63)) & 1ull) != 0ull;
        float4 b = make_float4(0.f, 0.f, 0.f, 0.f);
        float sc = 0.f;
        if (kept) {
            b  = reinterpret_cast<const float4*>(sel_box)[s];
            sc = sel_score[s];
        }
        reinterpret_cast<float4*>(out)[s] = b;
        out[4000 + s] = sc;
#pragma unroll
        for (int q = 0; q < 10; ++q)
            out[5000 + s*10 + q] = kept ? sel_lm[s*10 + q] : 0.f;
    }
}

extern "C" void kernel_launch(void* const* d_in, const int* in_sizes, int n_in,
                              void* d_out, int out_size, void* d_ws, size_t ws_size,
                              hipStream_t stream) {
    const float* loc    = (const float*)d_in[0];
    const float* conf   = (const float*)d_in[1];
    const float* land   = (const float*)d_in[2];
    const float* priors = (const float*)d_in[3];
    float* out = (float*)d_out;
    char* ws = (char*)d_ws;

    int* ctr                     = (int*)(ws + OFF_CTR);
    int* hist                    = (int*)(ws + OFF_HIST);
    unsigned long long* keys     = (unsigned long long*)(ws + OFF_KEYS);
    unsigned long long* keys2    = (unsigned long long*)(ws + OFF_KEYS2);
    float* sel_score             = (float*)(ws + OFF_SCORE);
    float* sel_box               = (float*)(ws + OFF_BOX);
    float* sel_lm                = (float*)(ws + OFF_LM);
    unsigned long long* sup      = (unsigned long long*)(ws + OFF_SUP);

    hipMemsetAsync(ws, 0, OFF_KEYS, stream); // zero counters + histogram

    int nb = (N_ANCH + 255) / 256; // 263
    k_score_compact<<<nb, 256, 0, stream>>>(conf, keys, hist, ctr);
    k_findcut<<<1, 1024, 0, stream>>>(hist, ctr);
    k_compact2<<<nb, 256, 0, stream>>>(keys, keys2, ctr);
    k_rank_select<<<CAP2 / 256, 256, 0, stream>>>(keys2, ctr, loc, land, priors,
                                                  sel_score, sel_box, sel_lm);
    k_sup<<<KCAP, 64, 0, stream>>>(sel_box, ctr, sup);
    k_nms_scan<<<1, 1024, 0, stream>>>(sup, ctr, sel_score, sel_box, sel_lm, out);
}

// Round 6
// 93.310 us; speedup vs baseline: 5.4128x; 1.0510x over previous
//
#include <hip/hip_runtime.h>
#include <stdint.h>

#define N_ANCH 67200
#define KCAP   1000
#define CONF_THR 0.7f
#define NMS_THR  0.4f

// score-bits histogram: scores in (0.7, 1.0) -> bits in (0x3F333333, 0x3F800000)
// span = 0x4CCCCD ulp; shift 10 -> 4916 live buckets, NBUCK = 4992 = 78*64.
#define BUCK_BASE 0x3F333333u
#define BUCK_SHIFT 10
#define NBUCK 4992
#define CAP2B 2048            // bitonic sort capacity (M2 ~ 1010)

// ---- workspace layout (bytes) ----
#define OFF_CTR   0           // int[0] = V (valid slot count)
#define OFF_KEYS  64          // N_ANCH*8 = 537600 -> 537664
#define OFF_SCORE 537664      // 1024*4  -> 541760
#define OFF_BOX   541760      // 1024*16 -> 558144 (16B aligned)
#define OFF_LM    558144      // 1024*40 -> 599104
#define OFF_SUP   599104      // 1000*16*8 = 128000 -> 727104 (~0.7 MB total)

__device__ inline unsigned long long shfl_xor_u64(unsigned long long v, int m) {
    unsigned int lo = (unsigned int)__shfl_xor((int)(v & 0xffffffffull), m, 64);
    unsigned int hi = (unsigned int)__shfl_xor((int)(v >> 32), m, 64);
    return ((unsigned long long)hi << 32) | lo;
}

// K1: pure elementwise. key = (score_bits<<32) | (0xFFFFFFFF - index) if score
// passes threshold, else 0. Dense write -> no atomics, no pre-zeroed state.
// Descending key order == lax.top_k order (ties -> ascending index); a passing
// candidate can never produce key 0 (score bits would be 0 -> s==0 < 0.7).
__global__ void k_front(const float* __restrict__ conf,
                        unsigned long long* __restrict__ keys) {
    int i = blockIdx.x * blockDim.x + threadIdx.x;
    if (i >= N_ANCH) return;
    float2 c = reinterpret_cast<const float2*>(conf)[i];
    float m  = fmaxf(c.x, c.y);
    float e0 = expf(c.x - m);
    float e1 = expf(c.y - m);
    float s  = e1 / (e0 + e1);
    unsigned long long k = 0ull;
    if (s > CONF_THR)
        k = ((unsigned long long)__float_as_uint(s) << 32)
          | (unsigned int)(0xFFFFFFFFu - (unsigned int)i);
    keys[i] = k;
}

// K2 (single block): histogram -> findcut -> compact -> bitonic sort ->
// decode top-V into slot order. All selection state lives in LDS; nothing
// needs pre-zeroing. Writes sel_score/sel_box/sel_lm and ctr[0]=V.
__global__ __launch_bounds__(1024) void k_back1(
        const unsigned long long* __restrict__ keys,
        const float* __restrict__ loc,
        const float* __restrict__ land,
        const float* __restrict__ priors,
        int* __restrict__ ctr,
        float* __restrict__ sel_score,
        float* __restrict__ sel_box,
        float* __restrict__ sel_lm) {
#pragma clang fp contract(off)
    __shared__ int hist[NBUCK];               // ~20 KB
    __shared__ unsigned long long sk[CAP2B];  // 16 KB
    __shared__ int scnt;
    __shared__ int sB;
    int tid = threadIdx.x;

    for (int t = tid; t < NBUCK; t += 1024) hist[t] = 0;
    if (tid == 0) scnt = 0;
    __syncthreads();

    // pass 1: histogram of candidate score bits
    for (int i = tid; i < N_ANCH; i += 1024) {
        unsigned long long k = keys[i];
        if (k) {
            unsigned int sb = (unsigned int)(k >> 32);
            int b = min((int)((sb - BUCK_BASE) >> BUCK_SHIFT), NBUCK - 1);
            atomicAdd(&hist[b], 1);
        }
    }
    __syncthreads();

    // findcut (wave 0): largest B with suffix-count >= KCAP, else 0
    if (tid < 64) {
        int lane = tid;
        int acc = 0, B = 0;
        bool found = false;
        for (int t = 0; t < NBUCK / 64 && !found; ++t) {
            int base = NBUCK - 64 * (t + 1);
            int c = hist[base + lane];
            int ssum = c;
#pragma unroll
            for (int off = 1; off < 64; off <<= 1)
                ssum += __shfl_xor(ssum, off, 64);
            if (acc + ssum >= KCAP) {
                for (int l = 63; l >= 0; --l) {
                    int cl = (int)__builtin_amdgcn_readlane((unsigned int)c, l);
                    if (acc + cl >= KCAP) { B = base + l; found = true; break; }
                    acc += cl;
                }
            } else {
                acc += ssum;
            }
        }
        if (lane == 0) sB = found ? B : 0;
    }
    __syncthreads();
    int B = sB;

    // pass 2 (L2-hot): compact bucket >= B into LDS. Every excluded key is
    // strictly smaller than every included one -> sorted sk == global top order.
    for (int i = tid; i < N_ANCH; i += 1024) {
        unsigned long long k = keys[i];
        if (k) {
            unsigned int sb = (unsigned int)(k >> 32);
            int b = min((int)((sb - BUCK_BASE) >> BUCK_SHIFT), NBUCK - 1);
            if (b >= B) {
                int pos = atomicAdd(&scnt, 1);
                if (pos < CAP2B) sk[pos] = k;
            }
        }
    }
    __syncthreads();
    int M2 = min(scnt, CAP2B);
    for (int t = tid; t < CAP2B; t += 1024)
        if (t >= M2) sk[t] = 0ull;

    // bitonic sort, descending, 2048 elems / 1024 threads (keys are unique)
    for (unsigned size = 2; size <= CAP2B; size <<= 1) {
        for (unsigned stride = size >> 1; stride > 0; stride >>= 1) {
            __syncthreads();
            unsigned i = 2 * tid - (tid & (stride - 1));
            unsigned j = i + stride;
            unsigned long long a = sk[i], b2 = sk[j];
            if ((a < b2) == ((i & size) == 0)) { sk[i] = b2; sk[j] = a; }
        }
    }
    __syncthreads();

    int V = min(M2, KCAP);
    if (tid == 0) ctr[0] = V;
    if (tid < V) {
        unsigned long long key = sk[tid];
        int r = tid;
        unsigned int a = 0xFFFFFFFFu - (unsigned int)(key & 0xFFFFFFFFull);
        sel_score[r] = __uint_as_float((unsigned int)(key >> 32));

        float pcx = priors[a*4+0], pcy = priors[a*4+1];
        float pw  = priors[a*4+2], ph  = priors[a*4+3];
        float l0 = loc[a*4+0], l1 = loc[a*4+1], l2 = loc[a*4+2], l3 = loc[a*4+3];
        // replicate reference op order exactly:
        float cx = pcx + (l0 * 0.1f) * pw;
        float cy = pcy + (l1 * 0.1f) * ph;
        float w  = pw * expf(l2 * 0.2f);
        float h  = ph * expf(l3 * 0.2f);
        float x1 = cx - w * 0.5f;
        float y1 = cy - h * 0.5f;
        sel_box[r*4+0] = x1 * 1280.0f;
        sel_box[r*4+1] = y1 * 1280.0f;
        sel_box[r*4+2] = (x1 + w) * 1280.0f;
        sel_box[r*4+3] = (y1 + h) * 1280.0f;
#pragma unroll
        for (int q = 0; q < 5; ++q) {
            float lx = land[a*10 + 2*q + 0];
            float ly = land[a*10 + 2*q + 1];
            sel_lm[r*10 + 2*q + 0] = (pcx + (lx * 0.1f) * pw) * 1280.0f;
            sel_lm[r*10 + 2*q + 1] = (pcy + (ly * 0.1f) * ph) * 1280.0f;
        }
    }
}

// K3: suppression bitmask rows. sup[i][g] bit l set iff j=g*64+l satisfies
// j>i, both valid, iou(b_i,b_j) > NMS_THR. Parallel across 1000 blocks.
__global__ void k_sup(const float* __restrict__ sel_box,
                      const int* __restrict__ ctr,
                      unsigned long long* __restrict__ sup) {
#pragma clang fp contract(off)
    int i = blockIdx.x;
    int V = min(ctr[0], KCAP);
    int lane = threadIdx.x; // 64 threads
    float ax1 = 0.f, ay1 = 0.f, ax2 = 0.f, ay2 = 0.f, aarea = 0.f;
    bool irow = (i < V);
    if (irow) {
        ax1 = sel_box[i*4+0]; ay1 = sel_box[i*4+1];
        ax2 = sel_box[i*4+2]; ay2 = sel_box[i*4+3];
        aarea = (ax2 - ax1) * (ay2 - ay1);
    }
    for (int g = 0; g < 16; ++g) {
        int j = g * 64 + lane;
        bool pred = false;
        if (irow && j < V && j > i) {
            float4 b = reinterpret_cast<const float4*>(sel_box)[j];
            float barea = (b.z - b.x) * (b.w - b.y);
            float ltx = fmaxf(ax1, b.x), lty = fmaxf(ay1, b.y);
            float rbx = fminf(ax2, b.z), rby = fminf(ay2, b.w);
            float wx = fmaxf(rbx - ltx, 0.0f);
            float wy = fmaxf(rby - lty, 0.0f);
            float inter = wx * wy;
            float iou = inter / (aarea + barea - inter + 1e-12f);
            pred = iou > NMS_THR;
        }
        unsigned long long mask = __ballot(pred);
        if (lane == 0) sup[i*16 + g] = mask;
    }
}

// K4: blocked greedy NMS scan, sparsity-aware. Diagonal resolve iterates only
// over kept bits whose rows are nonzero (ctz-driven; di has only j>i bits so
// the todo bookkeeping is exact). Cross-chunk OR-butterfly skipped when no
// lane contributes. XOR-swizzled LDS layout; one barrier per chunk.
// NOTE: readlane/readfirstlane return int; widen through unsigned int.
__global__ __launch_bounds__(1024) void k_nms_scan(
        const unsigned long long* __restrict__ sup,
        const int* __restrict__ ctr,
        const float* __restrict__ sel_score,
        const float* __restrict__ sel_box,
        const float* __restrict__ sel_lm,
        float* __restrict__ out) {
    __shared__ unsigned long long sup_r[1024][16]; // [row][w ^ (row&15)]
    __shared__ unsigned long long mshare[16];
    __shared__ unsigned long long keep_final[16];
    int tid = threadIdx.x;
    int wave = tid >> 6, lane = tid & 63;
    int V = min(ctr[0], KCAP);

    for (int idx = tid; idx < KCAP * 16; idx += 1024) {
        int r = idx >> 4, w = idx & 15;
        sup_r[r][w ^ (r & 15)] = sup[idx];
    }
    if (tid < 24 * 16) { // zero rows 1000..1023
        int r = 1000 + (tid >> 4), w = tid & 15;
        sup_r[r][w ^ (r & 15)] = 0ull;
    }
    unsigned long long kw;
    {
        int lo = wave * 64;
        kw = (V >= lo + 64) ? ~0ull : (V <= lo ? 0ull : ((1ull << (V - lo)) - 1ull));
    }
    __syncthreads();

    for (int c = 0; c < 16; ++c) {
        if (wave == c) {
            unsigned long long drow = sup_r[c*64 + lane][c ^ (lane & 15)];
            unsigned int dlo = (unsigned int)drow;
            unsigned int dhi = (unsigned int)(drow >> 32);
            unsigned long long nz = __ballot(drow != 0ull); // rows that can suppress
            unsigned long long m = kw;
            unsigned long long todo = m & nz;
            while (todo) {
                int i = (int)__builtin_ctzll(todo);
                i = __builtin_amdgcn_readfirstlane(i);
                unsigned long long di =
                    (((unsigned long long)(unsigned int)__builtin_amdgcn_readlane(dhi, i)) << 32)
                  |  (unsigned long long)(unsigned int)__builtin_amdgcn_readlane(dlo, i);
                m &= ~di;          // di only holds j>i bits
                todo &= ~di;       // suppressed rows never processed
                todo &= todo - 1ull; // clear bit i
            }
            kw = m;
            if (lane == 0) mshare[c] = m;
        }
        __syncthreads();
        if (wave > c) {
            unsigned long long m = mshare[c];
            unsigned long long contrib = ((m >> lane) & 1ull)
                ? sup_r[c*64 + lane][wave ^ (lane & 15)] : 0ull;
            if (__ballot(contrib != 0ull) != 0ull) {
#pragma unroll
                for (int off = 1; off < 64; off <<= 1)
                    contrib |= shfl_xor_u64(contrib, off);
                kw &= ~contrib;
            }
        }
    }
    if (lane == 0) keep_final[wave] = kw;
    __syncthreads();

    // write outputs: boxes [0,4000), scores [4000,5000), landms [5000,15000)
    for (int s = tid; s < KCAP; s += 1024) {
        bool kept = ((keep_final[s >> 6] >> (s & 63)) & 1ull) != 0ull;
        float4 b = make_float4(0.f, 0.f, 0.f, 0.f);
        float sc = 0.f;
        if (kept) {
            b  = reinterpret_cast<const float4*>(sel_box)[s];
            sc = sel_score[s];
        }
        reinterpret_cast<float4*>(out)[s] = b;
        out[4000 + s] = sc;
#pragma unroll
        for (int q = 0; q < 10; ++q)
            out[5000 + s*10 + q] = kept ? sel_lm[s*10 + q] : 0.f;
    }
}

extern "C" void kernel_launch(void* const* d_in, const int* in_sizes, int n_in,
                              void* d_out, int out_size, void* d_ws, size_t ws_size,
                              hipStream_t stream) {
    const float* loc    = (const float*)d_in[0];
    const float* conf   = (const float*)d_in[1];
    const float* land   = (const float*)d_in[2];
    const float* priors = (const float*)d_in[3];
    float* out = (float*)d_out;
    char* ws = (char*)d_ws;

    int* ctr                     = (int*)(ws + OFF_CTR);
    unsigned long long* keys     = (unsigned long long*)(ws + OFF_KEYS);
    float* sel_score             = (float*)(ws + OFF_SCORE);
    float* sel_box               = (float*)(ws + OFF_BOX);
    float* sel_lm                = (float*)(ws + OFF_LM);
    unsigned long long* sup      = (unsigned long long*)(ws + OFF_SUP);

    int nb = (N_ANCH + 255) / 256; // 263
    k_front<<<nb, 256, 0, stream>>>(conf, keys);
    k_back1<<<1, 1024, 0, stream>>>(keys, loc, land, priors, ctr,
                                    sel_score, sel_box, sel_lm);
    k_sup<<<KCAP, 64, 0, stream>>>(sel_box, ctr, sup);
    k_nms_scan<<<1, 1024, 0, stream>>>(sup, ctr, sel_score, sel_box, sel_lm, out);
}